// Round 2
// baseline (218.061 us; speedup 1.0000x reference)
//
#include <hip/hip_runtime.h>

#define EPS 1e-8f
#define TILE 512   // gaussians per block == blockDim.x

typedef float fvec4 __attribute__((ext_vector_type(4)));  // native vector: nt-builtin-compatible

__global__ __launch_bounds__(512) void gaussians_cov_kernel(
    const fvec4*  __restrict__ quat,
    const float*  __restrict__ scale,   // scale (N,3) as raw float stream
    fvec4*        __restrict__ out4,    // out (N,9) viewed as fvec4 stream
    int n)
{
    __shared__ float s_out[TILE * 9];    // 18 KB

    const int t    = threadIdx.x;
    const int base = blockIdx.x * TILE;

    // ---- per-thread compute ----
    const int i = base + t;
    if (i < n) {
        fvec4 q = __builtin_nontemporal_load(&quat[i]);   // coalesced 16 B/lane

        // direct per-thread scale load: lane i reads bytes [12i,12i+12) — contiguous
        // across the wave, same HBM traffic as the staged version, no barrier needed.
        float s0 = fabsf(scale[3*i + 0]) + EPS;
        float s1 = fabsf(scale[3*i + 1]) + EPS;
        float s2 = fabsf(scale[3*i + 2]) + EPS;

        float w = q.x, x = q.y, y = q.z, z = q.w;

        // R is quadratic in normalized q: fold normalization into t2 = 2/|q|^2 (no sqrt).
        float n2 = w*w + x*x + y*y + z*z;
        float t2 = 2.0f / n2;

        float xx = x*x*t2, yy = y*y*t2, zz = z*z*t2;
        float xy = x*y*t2, xz = x*z*t2, yz = y*z*t2;
        float wx = w*x*t2, wy = w*y*t2, wz = w*z*t2;

        float r00 = 1.0f - yy - zz, r01 = xy - wz,        r02 = xz + wy;
        float r10 = xy + wz,        r11 = 1.0f - xx - zz, r12 = yz - wx;
        float r20 = xz - wy,        r21 = yz + wx,        r22 = 1.0f - xx - yy;

        float a = s0*s0, b = s1*s1, c = s2*s2;

        // M = R diag(s^2) R^T, symmetric
        float m00 = r00*r00*a + r01*r01*b + r02*r02*c;
        float m01 = r00*r10*a + r01*r11*b + r02*r12*c;
        float m02 = r00*r20*a + r01*r21*b + r02*r22*c;
        float m11 = r10*r10*a + r11*r11*b + r12*r12*c;
        float m12 = r10*r20*a + r11*r21*b + r12*r22*c;
        float m22 = r20*r20*a + r21*r21*b + r22*r22*c;

        float* o = s_out + 9*t;                  // stride-9: 2 lanes/bank, free
        o[0] = m00; o[1] = m01; o[2] = m02;
        o[3] = m01; o[4] = m11; o[5] = m12;
        o[6] = m02; o[7] = m12; o[8] = m22;
    }
    __syncthreads();

    // ---- cooperative coalesced nt-store of the out tile (1152 fvec4 / block) ----
    {
        const int obase4 = blockIdx.x * (TILE * 9 / 4);
        const long long otot4 = (9LL * n) / 4;
        #pragma unroll
        for (int j = t; j < TILE * 9 / 4; j += TILE) {
            long long go = obase4 + (long long)j;
            if (go < otot4)
                __builtin_nontemporal_store(((fvec4*)s_out)[j], &out4[go]);
        }
    }
}

extern "C" void kernel_launch(void* const* d_in, const int* in_sizes, int n_in,
                              void* d_out, int out_size, void* d_ws, size_t ws_size,
                              hipStream_t stream) {
    const fvec4* quat  = (const fvec4*)d_in[0];
    const float* scale = (const float*)d_in[1];
    fvec4* out4 = (fvec4*)d_out;
    int n = in_sizes[0] / 4;   // quaternion is (N,4)

    int grid = (n + TILE - 1) / TILE;
    gaussians_cov_kernel<<<grid, TILE, 0, stream>>>(quat, scale, out4, n);
}

// Round 5
// 214.453 us; speedup vs baseline: 1.0168x; 1.0168x over previous
//
#include <hip/hip_runtime.h>

#define EPS 1e-8f
#define TILE 512   // gaussians per block == blockDim.x

typedef float fvec4 __attribute__((ext_vector_type(4)));  // native vector: nt-builtin-compatible

__global__ __launch_bounds__(512) void gaussians_cov_kernel(
    const fvec4* __restrict__ quat,
    const fvec4* __restrict__ scale4,   // scale (N,3) viewed as fvec4 stream
    fvec4*       __restrict__ out4,     // out (N,9) viewed as fvec4 stream
    int n)
{
    __shared__ float s_scale[TILE * 3];  // 6 KB
    __shared__ float s_out[TILE * 9];    // 18 KB

    const int t    = threadIdx.x;
    const int base = blockIdx.x * TILE;
    const int i    = base + t;

    // ---- issue the per-thread quat load BEFORE the barrier so its HBM latency
    //      overlaps the scale staging + barrier wait (compiler won't hoist across s_barrier)
    fvec4 q = {0.f, 0.f, 0.f, 0.f};
    if (i < n) q = __builtin_nontemporal_load(&quat[i]);   // coalesced 16 B/lane

    // ---- cooperative coalesced nt-load of the scale tile (384 fvec4 / block) ----
    {
        const int sbase4 = blockIdx.x * (TILE * 3 / 4);
        const int stot4  = (3 * n) / 4;
        if (t < TILE * 3 / 4) {
            int gi = sbase4 + t;
            if (gi < stot4)
                ((fvec4*)s_scale)[t] = __builtin_nontemporal_load(&scale4[gi]);
        }
    }
    __syncthreads();

    // ---- per-thread compute ----
    if (i < n) {
        float w = q.x, x = q.y, y = q.z, z = q.w;

        // R is quadratic in normalized q: fold normalization into t2 = 2/|q|^2 (no sqrt).
        float n2 = w*w + x*x + y*y + z*z;
        float t2 = 2.0f / n2;

        float xx = x*x*t2, yy = y*y*t2, zz = z*z*t2;
        float xy = x*y*t2, xz = x*z*t2, yz = y*z*t2;
        float wx = w*x*t2, wy = w*y*t2, wz = w*z*t2;

        float r00 = 1.0f - yy - zz, r01 = xy - wz,        r02 = xz + wy;
        float r10 = xy + wz,        r11 = 1.0f - xx - zz, r12 = yz - wx;
        float r20 = xz - wy,        r21 = yz + wx,        r22 = 1.0f - xx - yy;

        float s0 = fabsf(s_scale[3*t + 0]) + EPS;   // stride-3: 2 lanes/bank, free
        float s1 = fabsf(s_scale[3*t + 1]) + EPS;
        float s2 = fabsf(s_scale[3*t + 2]) + EPS;
        float a = s0*s0, b = s1*s1, c = s2*s2;

        // M = R diag(s^2) R^T, symmetric
        float m00 = r00*r00*a + r01*r01*b + r02*r02*c;
        float m01 = r00*r10*a + r01*r11*b + r02*r12*c;
        float m02 = r00*r20*a + r01*r21*b + r02*r22*c;
        float m11 = r10*r10*a + r11*r11*b + r12*r12*c;
        float m12 = r10*r20*a + r11*r21*b + r12*r22*c;
        float m22 = r20*r20*a + r21*r21*b + r22*r22*c;

        float* o = s_out + 9*t;                  // stride-9: 2 lanes/bank, free
        o[0] = m00; o[1] = m01; o[2] = m02;
        o[3] = m01; o[4] = m11; o[5] = m12;
        o[6] = m02; o[7] = m12; o[8] = m22;
    }
    __syncthreads();

    // ---- cooperative coalesced nt-store of the out tile (1152 fvec4 / block) ----
    {
        const int obase4 = blockIdx.x * (TILE * 9 / 4);
        const long long otot4 = (9LL * n) / 4;
        #pragma unroll
        for (int j = t; j < TILE * 9 / 4; j += TILE) {
            long long go = obase4 + (long long)j;
            if (go < otot4)
                __builtin_nontemporal_store(((fvec4*)s_out)[j], &out4[go]);
        }
    }
}

extern "C" void kernel_launch(void* const* d_in, const int* in_sizes, int n_in,
                              void* d_out, int out_size, void* d_ws, size_t ws_size,
                              hipStream_t stream) {
    const fvec4* quat   = (const fvec4*)d_in[0];
    const fvec4* scale4 = (const fvec4*)d_in[1];
    fvec4* out4 = (fvec4*)d_out;
    int n = in_sizes[0] / 4;   // quaternion is (N,4)

    int grid = (n + TILE - 1) / TILE;
    gaussians_cov_kernel<<<grid, TILE, 0, stream>>>(quat, scale4, out4, n);
}